// Round 1
// baseline (3796.460 us; speedup 1.0000x reference)
//
#include <hip/hip_runtime.h>

#define NROWS 51200   // C*S = 100*512
#define DD    256
#define NPROTO 2000
#define NCLSS 100

// ---------------------------------------------------------------------------
// p2[p] = sum_d protos[p][d]^2
// ---------------------------------------------------------------------------
__global__ void p2_kernel(const float* __restrict__ protos, float* __restrict__ p2) {
    int p = blockIdx.x * 256 + threadIdx.x;
    if (p >= NPROTO) return;
    const float4* row = reinterpret_cast<const float4*>(protos + (size_t)p * DD);
    float s = 0.f;
    #pragma unroll 8
    for (int k = 0; k < DD / 4; ++k) {
        float4 v = row[k];
        s = fmaf(v.x, v.x, s); s = fmaf(v.y, v.y, s);
        s = fmaf(v.z, v.z, s); s = fmaf(v.w, v.w, s);
    }
    p2[p] = s;
}

// ---------------------------------------------------------------------------
// X = relu(samples @ W^T + b)   [N,256] x [256,256]
// 64x64 tile, BK=32, 256 threads, 4x4 per thread (rows rg+16i, cols cg+16j)
// ---------------------------------------------------------------------------
__global__ __launch_bounds__(256) void hidden_kernel(
    const float* __restrict__ A, const float* __restrict__ W,
    const float* __restrict__ bias, float* __restrict__ X)
{
    __shared__ float sA[64][36];   // [row][k], pad 36 (16B-aligned rows, banks spread)
    __shared__ float sB[32][68];   // [k][col]
    const int t = threadIdx.x;
    const int rg = t >> 4, cg = t & 15;
    const int rowBase = blockIdx.x * 64;
    const int colBase = blockIdx.y * 64;

    float acc[4][4] = {};
    for (int kb = 0; kb < DD; kb += 32) {
        __syncthreads();
        // stage A tile 64x32 (2 float4 per thread)
        #pragma unroll
        for (int it = 0; it < 2; ++it) {
            int f4 = t + it * 256;           // 0..511
            int r = f4 >> 3, c4 = f4 & 7;
            float4 v = *reinterpret_cast<const float4*>(&A[(size_t)(rowBase + r) * DD + kb + c4 * 4]);
            *reinterpret_cast<float4*>(&sA[r][c4 * 4]) = v;
        }
        // stage B tile: sB[k][j] = W[(colBase+j)*256 + kb+k]  (transpose)
        #pragma unroll
        for (int it = 0; it < 2; ++it) {
            int f4 = t + it * 256;
            int j = f4 >> 3, k4 = f4 & 7;
            float4 v = *reinterpret_cast<const float4*>(&W[(size_t)(colBase + j) * DD + kb + k4 * 4]);
            sB[k4 * 4 + 0][j] = v.x; sB[k4 * 4 + 1][j] = v.y;
            sB[k4 * 4 + 2][j] = v.z; sB[k4 * 4 + 3][j] = v.w;
        }
        __syncthreads();
        #pragma unroll 8
        for (int k = 0; k < 32; ++k) {
            float a[4], b[4];
            #pragma unroll
            for (int i = 0; i < 4; ++i) a[i] = sA[rg + 16 * i][k];
            #pragma unroll
            for (int j = 0; j < 4; ++j) b[j] = sB[k][cg + 16 * j];
            #pragma unroll
            for (int i = 0; i < 4; ++i)
                #pragma unroll
                for (int j = 0; j < 4; ++j)
                    acc[i][j] = fmaf(a[i], b[j], acc[i][j]);
        }
    }
    #pragma unroll
    for (int i = 0; i < 4; ++i) {
        int r = rowBase + rg + 16 * i;
        #pragma unroll
        for (int j = 0; j < 4; ++j) {
            int c = colBase + cg + 16 * j;
            float v = acc[i][j] + bias[c];
            X[(size_t)r * DD + c] = fmaxf(v, 0.f);
        }
    }
}

// ---------------------------------------------------------------------------
// Fused flash-style: for each row, softmax over logits = 2*x.p - |p|^2,
// x_tilde = softmax @ protos.  BM=32 rows/block, PT=32 protos/tile.
// 256 threads: rg=t>>4 (16), cg=t&15 (16).
// Thread computes S for rows {rg, rg+16} x protos {cg, cg+16} and holds
// x_tilde acc for rows {rg,rg+16} x dims [cg*16, cg*16+16).
// LDS: two 32x256 fp32 tiles, float4-XOR-swizzled, exactly 64 KiB.
// ---------------------------------------------------------------------------
__global__ __launch_bounds__(256) void attn_kernel(
    const float* __restrict__ X, const float* __restrict__ protos,
    const float* __restrict__ p2g, float* __restrict__ XT)
{
    __shared__ float sx[32][256];
    __shared__ float sp[32][256];
    const int t = threadIdx.x;
    const int rg = t >> 4, cg = t & 15;
    const int rowBase = blockIdx.x * 32;

    // stage x tile (swizzled: f4 col c4 stored at c4 ^ (r&15))
    #pragma unroll
    for (int it = 0; it < 8; ++it) {
        int f4 = t + it * 256;               // 0..2047
        int r = f4 >> 6, c4 = f4 & 63;
        float4 v = *reinterpret_cast<const float4*>(&X[(size_t)(rowBase + r) * DD + c4 * 4]);
        *reinterpret_cast<float4*>(&sx[r][(c4 ^ (r & 15)) * 4]) = v;
    }

    float m[2] = { -3e38f, -3e38f };
    float l[2] = { 0.f, 0.f };
    float4 acc[2][4];
    #pragma unroll
    for (int i = 0; i < 2; ++i)
        #pragma unroll
        for (int q = 0; q < 4; ++q) acc[i][q] = make_float4(0.f, 0.f, 0.f, 0.f);

    const int nTiles = (NPROTO + 31) / 32;   // 63 (last tile: 16 real protos)
    for (int tile = 0; tile < nTiles; ++tile) {
        const int pBase = tile * 32;
        __syncthreads();                      // protect sp from previous PV reads
        #pragma unroll
        for (int it = 0; it < 8; ++it) {
            int f4 = t + it * 256;
            int r = f4 >> 6, c4 = f4 & 63;
            int gp = pBase + r;
            float4 v = make_float4(0.f, 0.f, 0.f, 0.f);
            if (gp < NPROTO)
                v = *reinterpret_cast<const float4*>(&protos[(size_t)gp * DD + c4 * 4]);
            *reinterpret_cast<float4*>(&sp[r][(c4 ^ (r & 15)) * 4]) = v;
        }
        __syncthreads();

        // ---- S = x . p  (rows {rg,rg+16}, protos {cg,cg+16}) ----
        float s[2][2] = { {0.f, 0.f}, {0.f, 0.f} };
        #pragma unroll 8
        for (int k4 = 0; k4 < 64; ++k4) {
            float4 xa0 = *reinterpret_cast<const float4*>(&sx[rg     ][(k4 ^ rg) * 4]);
            float4 xa1 = *reinterpret_cast<const float4*>(&sx[rg + 16][(k4 ^ rg) * 4]);
            float4 pb0 = *reinterpret_cast<const float4*>(&sp[cg     ][(k4 ^ cg) * 4]);
            float4 pb1 = *reinterpret_cast<const float4*>(&sp[cg + 16][(k4 ^ cg) * 4]);
            s[0][0] = fmaf(xa0.x, pb0.x, s[0][0]); s[0][0] = fmaf(xa0.y, pb0.y, s[0][0]);
            s[0][0] = fmaf(xa0.z, pb0.z, s[0][0]); s[0][0] = fmaf(xa0.w, pb0.w, s[0][0]);
            s[0][1] = fmaf(xa0.x, pb1.x, s[0][1]); s[0][1] = fmaf(xa0.y, pb1.y, s[0][1]);
            s[0][1] = fmaf(xa0.z, pb1.z, s[0][1]); s[0][1] = fmaf(xa0.w, pb1.w, s[0][1]);
            s[1][0] = fmaf(xa1.x, pb0.x, s[1][0]); s[1][0] = fmaf(xa1.y, pb0.y, s[1][0]);
            s[1][0] = fmaf(xa1.z, pb0.z, s[1][0]); s[1][0] = fmaf(xa1.w, pb0.w, s[1][0]);
            s[1][1] = fmaf(xa1.x, pb1.x, s[1][1]); s[1][1] = fmaf(xa1.y, pb1.y, s[1][1]);
            s[1][1] = fmaf(xa1.z, pb1.z, s[1][1]); s[1][1] = fmaf(xa1.w, pb1.w, s[1][1]);
        }

        // ---- logits, online softmax ----
        const int gp0 = pBase + cg, gp1 = gp0 + 16;
        const bool v0 = gp0 < NPROTO, v1 = gp1 < NPROTO;
        const float q0 = v0 ? p2g[gp0] : 0.f;
        const float q1 = v1 ? p2g[gp1] : 0.f;
        float w[2][2];
        #pragma unroll
        for (int i = 0; i < 2; ++i) {
            float l0 = v0 ? (2.f * s[i][0] - q0) : -1e30f;
            float l1 = v1 ? (2.f * s[i][1] - q1) : -1e30f;
            float tm = fmaxf(l0, l1);
            #pragma unroll
            for (int off = 1; off < 16; off <<= 1)
                tm = fmaxf(tm, __shfl_xor(tm, off, 64));
            float mn = fmaxf(m[i], tm);
            float sc = __expf(m[i] - mn);
            float w0 = __expf(l0 - mn);
            float w1 = __expf(l1 - mn);
            float ts = w0 + w1;
            #pragma unroll
            for (int off = 1; off < 16; off <<= 1)
                ts += __shfl_xor(ts, off, 64);
            l[i] = l[i] * sc + ts;
            m[i] = mn;
            #pragma unroll
            for (int q = 0; q < 4; ++q) {
                acc[i][q].x *= sc; acc[i][q].y *= sc;
                acc[i][q].z *= sc; acc[i][q].w *= sc;
            }
            w[i][0] = w0; w[i][1] = w1;
        }

        // ---- PV: acc[rows][dims cg*16..+15] += w * p  (w broadcast via shfl) ----
        #pragma unroll
        for (int jj = 0; jj < 2; ++jj) {
            #pragma unroll
            for (int mm = 0; mm < 16; ++mm) {
                const int j2 = jj * 16 + mm;
                const int src = rg * 16 + mm;
                float w0 = __shfl(w[0][jj], src, 64);
                float w1 = __shfl(w[1][jj], src, 64);
                const int key = j2 & 15;
                #pragma unroll
                for (int q = 0; q < 4; ++q) {
                    float4 pv = *reinterpret_cast<const float4*>(&sp[j2][((cg * 4 + q) ^ key) * 4]);
                    acc[0][q].x = fmaf(w0, pv.x, acc[0][q].x);
                    acc[0][q].y = fmaf(w0, pv.y, acc[0][q].y);
                    acc[0][q].z = fmaf(w0, pv.z, acc[0][q].z);
                    acc[0][q].w = fmaf(w0, pv.w, acc[0][q].w);
                    acc[1][q].x = fmaf(w1, pv.x, acc[1][q].x);
                    acc[1][q].y = fmaf(w1, pv.y, acc[1][q].y);
                    acc[1][q].z = fmaf(w1, pv.z, acc[1][q].z);
                    acc[1][q].w = fmaf(w1, pv.w, acc[1][q].w);
                }
            }
        }
    }

    // ---- epilogue: x_tilde = acc / l ----
    #pragma unroll
    for (int i = 0; i < 2; ++i) {
        float inv = 1.f / l[i];
        int r = rowBase + rg + 16 * i;
        #pragma unroll
        for (int q = 0; q < 4; ++q) {
            float4 o;
            o.x = acc[i][q].x * inv; o.y = acc[i][q].y * inv;
            o.z = acc[i][q].z * inv; o.w = acc[i][q].w * inv;
            *reinterpret_cast<float4*>(&XT[(size_t)r * DD + cg * 16 + q * 4]) = o;
        }
    }
}

// ---------------------------------------------------------------------------
// OUT[n][c] = sum_k X[n][k]*OW[c][k] + sum_k XT[n][k]*OW[c][256+k]
// block: 64 rows x 100 cols; thread: row r=t&63, colgroup g=t>>6 (25 cols)
// ---------------------------------------------------------------------------
__global__ __launch_bounds__(256) void out_kernel(
    const float* __restrict__ X, const float* __restrict__ XT,
    const float* __restrict__ OW, float* __restrict__ OUT)
{
    __shared__ float s_x[64][65];
    __shared__ float s_w[64][101];   // [k][c]
    const int t = threadIdx.x;
    const int r = t & 63, g = t >> 6;
    const int rowBase = blockIdx.x * 64;

    float acc[25] = {};
    for (int half = 0; half < 2; ++half) {
        const float* src = half ? XT : X;
        for (int kc = 0; kc < 4; ++kc) {
            const int kbase = kc * 64;
            __syncthreads();
            #pragma unroll
            for (int it = 0; it < 4; ++it) {
                int f4 = t + it * 256;        // 0..1023
                int rr = f4 >> 4, c4 = f4 & 15;
                float4 v = *reinterpret_cast<const float4*>(
                    &src[(size_t)(rowBase + rr) * DD + kbase + c4 * 4]);
                s_x[rr][c4 * 4 + 0] = v.x; s_x[rr][c4 * 4 + 1] = v.y;
                s_x[rr][c4 * 4 + 2] = v.z; s_x[rr][c4 * 4 + 3] = v.w;
            }
            #pragma unroll
            for (int it = 0; it < 25; ++it) {
                int idx = t + it * 256;       // 0..6399
                int c = idx >> 6, k = idx & 63;
                s_w[k][c] = OW[(size_t)c * 512 + half * 256 + kbase + k];
            }
            __syncthreads();
            #pragma unroll 4
            for (int k = 0; k < 64; ++k) {
                float xv = s_x[r][k];
                #pragma unroll
                for (int cc = 0; cc < 25; ++cc)
                    acc[cc] = fmaf(xv, s_w[k][g * 25 + cc], acc[cc]);
            }
        }
    }
    #pragma unroll
    for (int cc = 0; cc < 25; ++cc)
        OUT[(size_t)(rowBase + r) * NCLSS + g * 25 + cc] = acc[cc];
}

// ---------------------------------------------------------------------------
extern "C" void kernel_launch(void* const* d_in, const int* in_sizes, int n_in,
                              void* d_out, int out_size, void* d_ws, size_t ws_size,
                              hipStream_t stream) {
    const float* samples  = (const float*)d_in[0];
    const float* hidden_w = (const float*)d_in[1];
    const float* hidden_b = (const float*)d_in[2];
    const float* protos   = (const float*)d_in[3];
    const float* output_w = (const float*)d_in[4];
    float* out = (float*)d_out;

    char* ws = (char*)d_ws;
    float* X  = (float*)ws;                       // 51200*256*4 = 52,428,800 B
    float* XT = (float*)(ws + 52428800);          // 52,428,800 B
    float* P2 = (float*)(ws + 104857600);         // 8,000 B

    p2_kernel<<<8, 256, 0, stream>>>(protos, P2);
    hidden_kernel<<<dim3(800, 4), 256, 0, stream>>>(samples, hidden_w, hidden_b, X);
    attn_kernel<<<1600, 256, 0, stream>>>(X, protos, P2, XT);
    out_kernel<<<800, 256, 0, stream>>>(X, XT, output_w, out);
}

// Round 3
// 958.501 us; speedup vs baseline: 3.9608x; 3.9608x over previous
//
#include <hip/hip_runtime.h>

#define DD     256
#define NROWS  51200   // C*S
#define NPROTO 2000
#define NP2    2016    // padded to 63 tiles of 32
#define NT     63
#define NCLSS  100

typedef _Float16 h8 __attribute__((ext_vector_type(8)));
typedef float f32x16 __attribute__((ext_vector_type(16)));

// async global->LDS, 16B per lane, linear dest (wave-uniform base + lane*16)
__device__ __forceinline__ void gll16(const void* g, void* l) {
    __builtin_amdgcn_global_load_lds(
        (const __attribute__((address_space(1))) unsigned int*)g,
        (__attribute__((address_space(3))) unsigned int*)l, 16, 0, 0);
}

// ---------------------------------------------------------------------------
// p2[p] = |proto_p|^2 ; padded entries get +1e30 so logit = 2s - p2 -> -1e30
// ---------------------------------------------------------------------------
__global__ void p2_kernel(const float* __restrict__ protos, float* __restrict__ p2) {
    int p = blockIdx.x * 256 + threadIdx.x;
    if (p >= NP2) return;
    if (p >= NPROTO) { p2[p] = 1e30f; return; }
    const float4* row = reinterpret_cast<const float4*>(protos + (size_t)p * DD);
    float s = 0.f;
    #pragma unroll 8
    for (int k = 0; k < DD / 4; ++k) {
        float4 v = row[k];
        s = fmaf(v.x, v.x, s); s = fmaf(v.y, v.y, s);
        s = fmaf(v.z, v.z, s); s = fmaf(v.w, v.w, s);
    }
    p2[p] = s;
}

// ---------------------------------------------------------------------------
// Build fp16 proto images, pre-swizzled to the exact LDS image the attn
// kernel stages linearly with global_load_lds:
//  PHsw/PLsw: per tile [32 p][32 units of 8 f16], unit u stored at u^(p&7)
//  PTsw:      per tile [256 d][40 f16] (cols 0..31 = protos, 32..39 = 0 pad)
// ---------------------------------------------------------------------------
__global__ __launch_bounds__(256) void prep_kernel(
    const float* __restrict__ protos,
    _Float16* __restrict__ PHsw, _Float16* __restrict__ PLsw,
    _Float16* __restrict__ PTsw)
{
    const int id = blockIdx.x * 256 + threadIdx.x;   // 0..64511
    const int pg = id >> 5;                          // proto 0..2015
    const int u  = id & 31;                          // 8-elem unit
    const int tile = pg >> 5;
    const int p = pg & 31;

    float v[8];
    #pragma unroll
    for (int j = 0; j < 8; ++j) v[j] = 0.f;
    if (pg < NPROTO) {
        const float4 a = *(const float4*)(protos + (size_t)pg * DD + u * 8);
        const float4 b = *(const float4*)(protos + (size_t)pg * DD + u * 8 + 4);
        v[0]=a.x; v[1]=a.y; v[2]=a.z; v[3]=a.w;
        v[4]=b.x; v[5]=b.y; v[6]=b.z; v[7]=b.w;
    }
    h8 ph, pl;
    #pragma unroll
    for (int j = 0; j < 8; ++j) {
        _Float16 hv = (_Float16)v[j];
        ph[j] = hv;
        pl[j] = (_Float16)(v[j] - (float)hv);
    }
    const int u2 = u ^ (p & 7);
    *(h8*)(PHsw + (size_t)tile * 8192 + p * 256 + u2 * 8) = ph;
    *(h8*)(PLsw + (size_t)tile * 8192 + p * 256 + u2 * 8) = pl;
    _Float16* pt = PTsw + (size_t)tile * 10240;
    #pragma unroll
    for (int j = 0; j < 8; ++j)
        pt[(u * 8 + j) * 40 + p] = ph[j];
    if (p < 8) {
        #pragma unroll
        for (int j = 0; j < 8; ++j)
            pt[(u * 8 + j) * 40 + 32 + p] = (_Float16)0.f;
    }
}

// ---------------------------------------------------------------------------
// X16 = fp16( relu(samples @ W^T + b) )   [N,256]x[256,256], fp32 math
// ---------------------------------------------------------------------------
__global__ __launch_bounds__(256) void hidden_kernel(
    const float* __restrict__ A, const float* __restrict__ W,
    const float* __restrict__ bias, _Float16* __restrict__ X16)
{
    __shared__ float sA[64][36];
    __shared__ float sB[32][68];
    const int t = threadIdx.x;
    const int rg = t >> 4, cg = t & 15;
    const int rowBase = blockIdx.x * 64;
    const int colBase = blockIdx.y * 64;

    float acc[4][4] = {};
    for (int kb = 0; kb < DD; kb += 32) {
        __syncthreads();
        #pragma unroll
        for (int it = 0; it < 2; ++it) {
            int f4 = t + it * 256;
            int r = f4 >> 3, c4 = f4 & 7;
            float4 v = *reinterpret_cast<const float4*>(&A[(size_t)(rowBase + r) * DD + kb + c4 * 4]);
            *reinterpret_cast<float4*>(&sA[r][c4 * 4]) = v;
        }
        #pragma unroll
        for (int it = 0; it < 2; ++it) {
            int f4 = t + it * 256;
            int j = f4 >> 3, k4 = f4 & 7;
            float4 v = *reinterpret_cast<const float4*>(&W[(size_t)(colBase + j) * DD + kb + k4 * 4]);
            sB[k4 * 4 + 0][j] = v.x; sB[k4 * 4 + 1][j] = v.y;
            sB[k4 * 4 + 2][j] = v.z; sB[k4 * 4 + 3][j] = v.w;
        }
        __syncthreads();
        #pragma unroll 8
        for (int k = 0; k < 32; ++k) {
            float a[4], b[4];
            #pragma unroll
            for (int i = 0; i < 4; ++i) a[i] = sA[rg + 16 * i][k];
            #pragma unroll
            for (int j = 0; j < 4; ++j) b[j] = sB[k][cg + 16 * j];
            #pragma unroll
            for (int i = 0; i < 4; ++i)
                #pragma unroll
                for (int j = 0; j < 4; ++j)
                    acc[i][j] = fmaf(a[i], b[j], acc[i][j]);
        }
    }
    #pragma unroll
    for (int i = 0; i < 4; ++i) {
        int r = rowBase + rg + 16 * i;
        #pragma unroll
        for (int j = 0; j < 4; ++j) {
            int c = colBase + cg + 16 * j;
            float v = acc[i][j] + bias[c];
            X16[(size_t)r * DD + c] = (_Float16)fmaxf(v, 0.f);
        }
    }
}

// ---------------------------------------------------------------------------
// MFMA flash attention over prototypes.
// Block = 4 waves x 32 rows = 128 rows; tile = 32 protos; K=256.
// Per wave: S(32x32) via 16 kchunks x (PH + PL) mfma_32x32x16_f16,
// logits = 2S - p2, defer-max online softmax (THR=8: exp(8)=2981 stays
// inside f16 range 65504 -- THR=20 overflowed f16 -> inf -> NaN),
// q->LDS->A-frag, PV into 8 d-fragments (256 dims).
// C layout (m74/m101): col = lane&31, row = (reg&3)+8*(reg>>2)+4*(lane>>5)
// A/B: row/col = lane&31, k = 8*(lane>>5)+i
// ---------------------------------------------------------------------------
__global__ __launch_bounds__(256, 2) void attn_kernel(
    const _Float16* __restrict__ XH, const _Float16* __restrict__ PHsw,
    const _Float16* __restrict__ PLsw, const _Float16* __restrict__ PTsw,
    const float* __restrict__ P2, _Float16* __restrict__ XT)
{
    __shared__ __align__(16) _Float16 sPH[32 * 256];   // 16 KiB, swizzled units
    __shared__ __align__(16) _Float16 sPL[32 * 256];   // 16 KiB
    __shared__ __align__(16) _Float16 sPT[256 * 40];   // 20 KiB, stride-40 rows
    __shared__ __align__(16) _Float16 sQ[4][32 * 40];  // 10 KiB, per-wave q tiles

    const int t = threadIdx.x;
    const int wv = t >> 6;
    const int lane = t & 63;
    const int lid = lane & 31;
    const int h = lane >> 5;
    const int rowBase = blockIdx.x * 128 + wv * 32;
    const int swz = lid & 7;

    // x-hat A-fragments, resident in registers (64 VGPR)
    h8 xa[16];
    {
        const _Float16* xrow = XH + (size_t)(rowBase + lid) * DD + 8 * h;
        #pragma unroll
        for (int kc = 0; kc < 16; ++kc)
            xa[kc] = *(const h8*)(xrow + kc * 16);
    }

    f32x16 acc[8];
    #pragma unroll
    for (int f = 0; f < 8; ++f)
        #pragma unroll
        for (int r = 0; r < 16; ++r) acc[f][r] = 0.f;

    float m[16], l[16];
    #pragma unroll
    for (int r = 0; r < 16; ++r) { m[r] = -3e38f; l[r] = 0.f; }

    for (int tile = 0; tile < NT; ++tile) {
        // ---- stage proto tile (52 KiB) linearly: swizzle is baked in global ----
        {
            const _Float16* g0 = PHsw + (size_t)tile * 8192;
            const _Float16* g1 = PLsw + (size_t)tile * 8192;
            const _Float16* g2 = PTsw + (size_t)tile * 10240;
            #pragma unroll
            for (int i = 0; i < 4; ++i) gll16(g0 + (i * 256 + t) * 8, sPH + (i * 256 + t) * 8);
            #pragma unroll
            for (int i = 0; i < 4; ++i) gll16(g1 + (i * 256 + t) * 8, sPL + (i * 256 + t) * 8);
            #pragma unroll
            for (int i = 0; i < 5; ++i) gll16(g2 + (i * 256 + t) * 8, sPT + (i * 256 + t) * 8);
        }
        __syncthreads();   // drains vmcnt -> staged data visible

        // ---- QK: S = x_hat . (p_hi + p_lo) ----
        f32x16 S;
        #pragma unroll
        for (int r = 0; r < 16; ++r) S[r] = 0.f;
        {
            const _Float16* phrow = sPH + lid * 256;
            const _Float16* plrow = sPL + lid * 256;
            #pragma unroll
            for (int kc = 0; kc < 16; ++kc) {
                const int u = ((kc * 2 + h) ^ swz) * 8;
                h8 bh = *(const h8*)(phrow + u);
                h8 bl = *(const h8*)(plrow + u);
                S = __builtin_amdgcn_mfma_f32_32x32x16_f16(xa[kc], bh, S, 0, 0, 0);
                S = __builtin_amdgcn_mfma_f32_32x32x16_f16(xa[kc], bl, S, 0, 0, 0);
            }
        }

        // ---- logits (in place) ----
        const float p2v = P2[tile * 32 + lid];
        #pragma unroll
        for (int r = 0; r < 16; ++r) S[r] = 2.f * S[r] - p2v;

        // ---- defer-max online softmax (THR=8, f16-safe) ----
        float w[16];
        float ex = S[0] - m[0];
        #pragma unroll
        for (int r = 1; r < 16; ++r) ex = fmaxf(ex, S[r] - m[r]);
        if (__any(ex > 8.f)) {
            #pragma unroll
            for (int r = 0; r < 16; ++r) w[r] = S[r];
            #pragma unroll
            for (int msk = 1; msk < 32; msk <<= 1)
                #pragma unroll
                for (int r = 0; r < 16; ++r)
                    w[r] = fmaxf(w[r], __shfl_xor(w[r], msk, 64));
            #pragma unroll
            for (int r = 0; r < 16; ++r) {
                float mn = fmaxf(m[r], w[r]);
                float sc = __expf(m[r] - mn);
                m[r] = mn; l[r] *= sc;
                #pragma unroll
                for (int f = 0; f < 8; ++f) acc[f][r] *= sc;
            }
        }
        #pragma unroll
        for (int r = 0; r < 16; ++r) w[r] = __expf(S[r] - m[r]);

        // ---- write q tile (f16) for PV A-fragments ----
        {
            _Float16* q = sQ[wv];
            #pragma unroll
            for (int r = 0; r < 16; ++r) {
                const int n = (r & 3) + 8 * (r >> 2) + 4 * h;
                q[n * 40 + lid] = (_Float16)w[r];
            }
        }

        // ---- row-sum of weights (within 32-lane half) ----
        #pragma unroll
        for (int msk = 1; msk < 32; msk <<= 1)
            #pragma unroll
            for (int r = 0; r < 16; ++r)
                w[r] += __shfl_xor(w[r], msk, 64);
        #pragma unroll
        for (int r = 0; r < 16; ++r) l[r] += w[r];

        // ---- PV: acc += q @ P ----
        {
            const _Float16* q = sQ[wv] + lid * 40 + 8 * h;
            h8 qa0 = *(const h8*)(q);
            h8 qa1 = *(const h8*)(q + 16);
            #pragma unroll
            for (int f = 0; f < 8; ++f) {
                const _Float16* pt = sPT + (f * 32 + lid) * 40 + 8 * h;
                h8 b0 = *(const h8*)(pt);
                h8 b1 = *(const h8*)(pt + 16);
                acc[f] = __builtin_amdgcn_mfma_f32_32x32x16_f16(qa0, b0, acc[f], 0, 0, 0);
                acc[f] = __builtin_amdgcn_mfma_f32_32x32x16_f16(qa1, b1, acc[f], 0, 0, 0);
            }
        }
        __syncthreads();   // protect LDS tiles before next stage
    }

    // ---- epilogue: x_tilde = acc / l, write fp16 ----
    #pragma unroll
    for (int r = 0; r < 16; ++r) {
        const float inv = 1.f / l[r];
        const int n = rowBase + (r & 3) + 8 * (r >> 2) + 4 * h;
        #pragma unroll
        for (int f = 0; f < 8; ++f)
            XT[(size_t)n * DD + f * 32 + lid] = (_Float16)(acc[f][r] * inv);
    }
}

// ---------------------------------------------------------------------------
// OUT[n][c] = x @ OW[:, :256]^T + x_tilde @ OW[:, 256:]^T  (fp16 in, fp32 math)
// ---------------------------------------------------------------------------
__global__ __launch_bounds__(256) void out_kernel(
    const _Float16* __restrict__ X, const _Float16* __restrict__ XT,
    const float* __restrict__ OW, float* __restrict__ OUT)
{
    __shared__ float s_x[64][65];
    __shared__ float s_w[64][101];
    const int t = threadIdx.x;
    const int r = t & 63, g = t >> 6;
    const int rowBase = blockIdx.x * 64;

    float acc[25] = {};
    for (int half = 0; half < 2; ++half) {
        const _Float16* src = half ? XT : X;
        for (int kc = 0; kc < 4; ++kc) {
            const int kbase = kc * 64;
            __syncthreads();
            #pragma unroll
            for (int it = 0; it < 2; ++it) {
                int f8 = t + it * 256;            // 0..511
                int rr = f8 >> 3, c8 = f8 & 7;
                h8 v = *(const h8*)(src + (size_t)(rowBase + rr) * DD + kbase + c8 * 8);
                #pragma unroll
                for (int j = 0; j < 8; ++j) s_x[rr][c8 * 8 + j] = (float)v[j];
            }
            #pragma unroll
            for (int it = 0; it < 25; ++it) {
                int idx = t + it * 256;
                int c = idx >> 6, k = idx & 63;
                s_w[k][c] = OW[(size_t)c * 512 + half * 256 + kbase + k];
            }
            __syncthreads();
            #pragma unroll 4
            for (int k = 0; k < 64; ++k) {
                float xv = s_x[r][k];
                #pragma unroll
                for (int cc = 0; cc < 25; ++cc)
                    acc[cc] = fmaf(xv, s_w[k][g * 25 + cc], acc[cc]);
            }
        }
    }
    #pragma unroll
    for (int cc = 0; cc < 25; ++cc)
        OUT[(size_t)(rowBase + r) * NCLSS + g * 25 + cc] = acc[cc];
}

// ---------------------------------------------------------------------------
extern "C" void kernel_launch(void* const* d_in, const int* in_sizes, int n_in,
                              void* d_out, int out_size, void* d_ws, size_t ws_size,
                              hipStream_t stream) {
    const float* samples  = (const float*)d_in[0];
    const float* hidden_w = (const float*)d_in[1];
    const float* hidden_b = (const float*)d_in[2];
    const float* protos   = (const float*)d_in[3];
    const float* output_w = (const float*)d_in[4];
    float* out = (float*)d_out;

    char* ws = (char*)d_ws;
    _Float16* XH   = (_Float16*)(ws);                  // 51200*256*2 = 26,214,400
    _Float16* XT   = (_Float16*)(ws + 26214400);       // 26,214,400
    _Float16* PHsw = (_Float16*)(ws + 52428800);       // 63*8192*2  =  1,032,192
    _Float16* PLsw = (_Float16*)(ws + 53460992);       //               1,032,192
    _Float16* PTsw = (_Float16*)(ws + 54493184);       // 63*10240*2 =  1,290,240
    float*    P2   = (float*)   (ws + 55783424);       // 2016*4

    p2_kernel<<<8, 256, 0, stream>>>(protos, P2);
    prep_kernel<<<252, 256, 0, stream>>>(protos, PHsw, PLsw, PTsw);
    hidden_kernel<<<dim3(800, 4), 256, 0, stream>>>(samples, hidden_w, hidden_b, XH);
    attn_kernel<<<400, 256, 0, stream>>>(XH, PHsw, PLsw, PTsw, P2, XT);
    out_kernel<<<800, 256, 0, stream>>>(XH, XT, output_w, out);
}

// Round 4
// 457.928 us; speedup vs baseline: 8.2905x; 2.0931x over previous
//
#include <hip/hip_runtime.h>

#define DD     256
#define NROWS  51200   // C*S
#define NPROTO 2000
#define NP2    2016    // padded to 63 tiles of 32
#define NT     63
#define NCLSS  100

typedef _Float16 h8 __attribute__((ext_vector_type(8)));
typedef float f32x16 __attribute__((ext_vector_type(16)));

// async global->LDS, 16B per lane, linear dest (wave-uniform base + lane*16)
__device__ __forceinline__ void gll16(const void* g, void* l) {
    __builtin_amdgcn_global_load_lds(
        (const __attribute__((address_space(1))) unsigned int*)g,
        (__attribute__((address_space(3))) unsigned int*)l, 16, 0, 0);
}

// ---------------------------------------------------------------------------
// p2[p] = |proto_p|^2 ; padded entries get +1e30 so logit -> -1e30
// ---------------------------------------------------------------------------
__global__ void p2_kernel(const float* __restrict__ protos, float* __restrict__ p2) {
    int p = blockIdx.x * 256 + threadIdx.x;
    if (p >= NP2) return;
    if (p >= NPROTO) { p2[p] = 1e30f; return; }
    const float4* row = reinterpret_cast<const float4*>(protos + (size_t)p * DD);
    float s = 0.f;
    #pragma unroll 8
    for (int k = 0; k < DD / 4; ++k) {
        float4 v = row[k];
        s = fmaf(v.x, v.x, s); s = fmaf(v.y, v.y, s);
        s = fmaf(v.z, v.z, s); s = fmaf(v.w, v.w, s);
    }
    p2[p] = s;
}

// ---------------------------------------------------------------------------
// Proto images (f16 hi only):
//  PHsw: per tile [32 p][32 units of 8 f16], unit u stored at u^(p&7)
//  PTsw: per tile [256 d][40 f16] (cols 0..31 = protos, 32..39 = 0 pad)
// ---------------------------------------------------------------------------
__global__ __launch_bounds__(256) void prep_proto(
    const float* __restrict__ protos,
    _Float16* __restrict__ PHsw, _Float16* __restrict__ PTsw)
{
    const int id = blockIdx.x * 256 + threadIdx.x;   // 0..64511
    const int pg = id >> 5;                          // proto 0..2015
    const int u  = id & 31;
    const int tile = pg >> 5;
    const int p = pg & 31;

    float v[8];
    #pragma unroll
    for (int j = 0; j < 8; ++j) v[j] = 0.f;
    if (pg < NPROTO) {
        const float4 a = *(const float4*)(protos + (size_t)pg * DD + u * 8);
        const float4 b = *(const float4*)(protos + (size_t)pg * DD + u * 8 + 4);
        v[0]=a.x; v[1]=a.y; v[2]=a.z; v[3]=a.w;
        v[4]=b.x; v[5]=b.y; v[6]=b.z; v[7]=b.w;
    }
    h8 ph;
    #pragma unroll
    for (int j = 0; j < 8; ++j) ph[j] = (_Float16)v[j];
    *(h8*)(PHsw + (size_t)tile * 8192 + p * 256 + (u ^ (p & 7)) * 8) = ph;
    _Float16* pt = PTsw + (size_t)tile * 10240;
    #pragma unroll
    for (int j = 0; j < 8; ++j)
        pt[(u * 8 + j) * 40 + p] = ph[j];
    if (p < 8) {
        #pragma unroll
        for (int j = 0; j < 8; ++j)
            pt[(u * 8 + j) * 40 + 32 + p] = (_Float16)0.f;
    }
}

// ---------------------------------------------------------------------------
// WHsw: 8 tiles x [32 cols][32 units], B[k][c]=W[c][k], unit u at u^(c&7)
// ---------------------------------------------------------------------------
__global__ __launch_bounds__(256) void prep_w(
    const float* __restrict__ W, _Float16* __restrict__ WHsw)
{
    const int id = blockIdx.x * 256 + threadIdx.x;   // 0..8191
    const int c = id >> 5;                           // 0..255
    const int u = id & 31;
    const float4 a = *(const float4*)(W + (size_t)c * DD + u * 8);
    const float4 b = *(const float4*)(W + (size_t)c * DD + u * 8 + 4);
    h8 hv;
    hv[0]=(_Float16)a.x; hv[1]=(_Float16)a.y; hv[2]=(_Float16)a.z; hv[3]=(_Float16)a.w;
    hv[4]=(_Float16)b.x; hv[5]=(_Float16)b.y; hv[6]=(_Float16)b.z; hv[7]=(_Float16)b.w;
    *(h8*)(WHsw + (size_t)(c >> 5) * 8192 + (c & 31) * 256 + ((u ^ (c & 7)) * 8)) = hv;
}

// ---------------------------------------------------------------------------
// OWsw: 8 chunks (ct 0..3 x kh 0..1) x [32 cols][32 units]; cols 100..127 zero
// chunk = (c>>5)*2 + (u>>5), B[k][c] = OW[c][k], k = u*8..
// ---------------------------------------------------------------------------
__global__ __launch_bounds__(256) void prep_ow(
    const float* __restrict__ OW, _Float16* __restrict__ OWsw)
{
    const int id = blockIdx.x * 256 + threadIdx.x;   // 0..8191
    const int c = id >> 6;                           // 0..127
    const int u = id & 63;                           // 0..63
    float v[8];
    #pragma unroll
    for (int j = 0; j < 8; ++j) v[j] = 0.f;
    if (c < NCLSS) {
        const float4 a = *(const float4*)(OW + (size_t)c * 512 + u * 8);
        const float4 b = *(const float4*)(OW + (size_t)c * 512 + u * 8 + 4);
        v[0]=a.x; v[1]=a.y; v[2]=a.z; v[3]=a.w;
        v[4]=b.x; v[5]=b.y; v[6]=b.z; v[7]=b.w;
    }
    h8 hv;
    #pragma unroll
    for (int j = 0; j < 8; ++j) hv[j] = (_Float16)v[j];
    const int chunk = (c >> 5) * 2 + (u >> 5);
    const int u5 = u & 31;
    *(h8*)(OWsw + (size_t)chunk * 8192 + (c & 31) * 256 + ((u5 ^ (c & 7)) * 8)) = hv;
}

// ---------------------------------------------------------------------------
// hidden: XH = f16(relu(samples @ W^T + b)), MFMA 32x32x16, 4 waves x 32 rows
// ---------------------------------------------------------------------------
__global__ __launch_bounds__(256, 2) void hidden_kernel(
    const float* __restrict__ A, const _Float16* __restrict__ WHsw,
    const float* __restrict__ bias, _Float16* __restrict__ XH)
{
    __shared__ __align__(16) _Float16 sW[2][32 * 256];
    __shared__ float sBias[256];
    const int t = threadIdx.x;
    const int wv = t >> 6, lane = t & 63, lid = lane & 31, h = lane >> 5;
    const int rowBase = blockIdx.x * 128 + wv * 32;
    const int swz = lid & 7;

    sBias[t] = bias[t];

    h8 xa[16];
    {
        const float* arow = A + (size_t)(rowBase + lid) * DD + 8 * h;
        #pragma unroll
        for (int kc = 0; kc < 16; ++kc) {
            float4 va = *(const float4*)(arow + kc * 16);
            float4 vb = *(const float4*)(arow + kc * 16 + 4);
            h8 x;
            x[0]=(_Float16)va.x; x[1]=(_Float16)va.y; x[2]=(_Float16)va.z; x[3]=(_Float16)va.w;
            x[4]=(_Float16)vb.x; x[5]=(_Float16)vb.y; x[6]=(_Float16)vb.z; x[7]=(_Float16)vb.w;
            xa[kc] = x;
        }
    }
    #pragma unroll
    for (int i = 0; i < 4; ++i)
        gll16(WHsw + (i * 256 + t) * 8, &sW[0][(i * 256 + t) * 8]);
    __syncthreads();

    #pragma unroll
    for (int ct = 0; ct < 8; ++ct) {
        const int buf = ct & 1;
        if (ct + 1 < 8) {
            const _Float16* g = WHsw + (size_t)(ct + 1) * 8192;
            #pragma unroll
            for (int i = 0; i < 4; ++i)
                gll16(g + (i * 256 + t) * 8, &sW[buf ^ 1][(i * 256 + t) * 8]);
        }
        f32x16 c0, c1;
        #pragma unroll
        for (int r = 0; r < 16; ++r) { c0[r] = 0.f; c1[r] = 0.f; }
        const _Float16* wrow = &sW[buf][lid * 256];
        #pragma unroll
        for (int kc = 0; kc < 16; kc += 2) {
            h8 b0 = *(const h8*)(wrow + (((kc    ) * 2 + h) ^ swz) * 8);
            h8 b1 = *(const h8*)(wrow + (((kc + 1) * 2 + h) ^ swz) * 8);
            c0 = __builtin_amdgcn_mfma_f32_32x32x16_f16(xa[kc],     b0, c0, 0, 0, 0);
            c1 = __builtin_amdgcn_mfma_f32_32x32x16_f16(xa[kc + 1], b1, c1, 0, 0, 0);
        }
        const float bv = sBias[ct * 32 + lid];
        #pragma unroll
        for (int r = 0; r < 16; ++r) {
            const int n = rowBase + (r & 3) + 8 * (r >> 2) + 4 * h;
            float v = c0[r] + c1[r] + bv;
            XH[(size_t)n * DD + ct * 32 + lid] = (_Float16)fmaxf(v, 0.f);
        }
        __syncthreads();
    }
}

// ---------------------------------------------------------------------------
// MFMA flash attention, double-buffered staging, ones-column denominator.
// 4 waves x 32 rows = 128 rows/block, tile = 32 protos, K=256 (hi-only f16).
// C layout: col=lane&31, row=(reg&3)+8*(reg>>2)+4*(lane>>5); A/B: k=8*(lane>>5)+i
// ---------------------------------------------------------------------------
__global__ __launch_bounds__(256, 1) void attn_kernel(
    const _Float16* __restrict__ XH, const _Float16* __restrict__ PHsw,
    const _Float16* __restrict__ PTsw, const float* __restrict__ P2,
    _Float16* __restrict__ XT)
{
    __shared__ __align__(16) _Float16 sPH[2][32 * 256];   // 32 KiB
    __shared__ __align__(16) _Float16 sPT[2][256 * 40];   // 40 KiB
    __shared__ __align__(16) _Float16 sQ[4][32 * 40];     // 10 KiB
    __shared__ float sP2[NP2];                            // 8 KiB

    const int t = threadIdx.x;
    const int wv = t >> 6, lane = t & 63, lid = lane & 31, h = lane >> 5;
    const int rowBase = blockIdx.x * 128 + wv * 32;
    const int swz = lid & 7;

    for (int i = t; i < NP2; i += 256) sP2[i] = P2[i];

    h8 xa[16];
    {
        const _Float16* xrow = XH + (size_t)(rowBase + lid) * DD + 8 * h;
        #pragma unroll
        for (int kc = 0; kc < 16; ++kc)
            xa[kc] = *(const h8*)(xrow + kc * 16);
    }

    f32x16 acc[8], accL;
    #pragma unroll
    for (int f = 0; f < 8; ++f)
        #pragma unroll
        for (int r = 0; r < 16; ++r) acc[f][r] = 0.f;
    #pragma unroll
    for (int r = 0; r < 16; ++r) accL[r] = 0.f;

    float m[16];
    #pragma unroll
    for (int r = 0; r < 16; ++r) m[r] = -3e38f;

    h8 ones;
    #pragma unroll
    for (int j = 0; j < 8; ++j) ones[j] = (_Float16)1.f;

    // prologue: stage tile 0 into buf 0
    {
        #pragma unroll
        for (int i = 0; i < 4; ++i) gll16(PHsw + (i * 256 + t) * 8, &sPH[0][(i * 256 + t) * 8]);
        #pragma unroll
        for (int i = 0; i < 5; ++i) gll16(PTsw + (i * 256 + t) * 8, &sPT[0][(i * 256 + t) * 8]);
    }
    __syncthreads();

    for (int tile = 0; tile < NT; ++tile) {
        const int buf = tile & 1;
        // issue next-tile staging first (lands under this tile's compute)
        if (tile + 1 < NT) {
            const _Float16* g0 = PHsw + (size_t)(tile + 1) * 8192;
            const _Float16* g2 = PTsw + (size_t)(tile + 1) * 10240;
            #pragma unroll
            for (int i = 0; i < 4; ++i) gll16(g0 + (i * 256 + t) * 8, &sPH[buf ^ 1][(i * 256 + t) * 8]);
            #pragma unroll
            for (int i = 0; i < 5; ++i) gll16(g2 + (i * 256 + t) * 8, &sPT[buf ^ 1][(i * 256 + t) * 8]);
        }
        const float p2v = sP2[tile * 32 + lid];

        // ---- QK (hi only), 2 independent chains ----
        f32x16 S0, S1;
        #pragma unroll
        for (int r = 0; r < 16; ++r) { S0[r] = 0.f; S1[r] = 0.f; }
        {
            const _Float16* phrow = &sPH[buf][lid * 256];
            #pragma unroll
            for (int kc = 0; kc < 16; kc += 2) {
                h8 b0 = *(const h8*)(phrow + (((kc    ) * 2 + h) ^ swz) * 8);
                h8 b1 = *(const h8*)(phrow + (((kc + 1) * 2 + h) ^ swz) * 8);
                S0 = __builtin_amdgcn_mfma_f32_32x32x16_f16(xa[kc],     b0, S0, 0, 0, 0);
                S1 = __builtin_amdgcn_mfma_f32_32x32x16_f16(xa[kc + 1], b1, S1, 0, 0, 0);
            }
        }
        float S[16];
        #pragma unroll
        for (int r = 0; r < 16; ++r) S[r] = 2.f * (S0[r] + S1[r]) - p2v;

        // ---- defer-max online softmax (THR=8, f16-safe) ----
        float ex = S[0] - m[0];
        #pragma unroll
        for (int r = 1; r < 16; ++r) ex = fmaxf(ex, S[r] - m[r]);
        if (__any(ex > 8.f)) {
            float w[16];
            #pragma unroll
            for (int r = 0; r < 16; ++r) w[r] = S[r];
            #pragma unroll
            for (int msk = 1; msk < 32; msk <<= 1)
                #pragma unroll
                for (int r = 0; r < 16; ++r)
                    w[r] = fmaxf(w[r], __shfl_xor(w[r], msk, 64));
            #pragma unroll
            for (int r = 0; r < 16; ++r) {
                float mn = fmaxf(m[r], w[r]);
                float sc = __expf(m[r] - mn);
                m[r] = mn;
                #pragma unroll
                for (int f = 0; f < 8; ++f) acc[f][r] *= sc;
                accL[r] *= sc;
            }
        }
        float w[16];
        #pragma unroll
        for (int r = 0; r < 16; ++r) w[r] = __expf(S[r] - m[r]);

        // ---- q tile to LDS (wave-local) ----
        {
            _Float16* q = sQ[wv];
            #pragma unroll
            for (int r = 0; r < 16; ++r) {
                const int n = (r & 3) + 8 * (r >> 2) + 4 * h;
                q[n * 40 + lid] = (_Float16)w[r];
            }
        }

        // ---- PV + ones-column denominator ----
        {
            const _Float16* q = sQ[wv] + lid * 40 + 8 * h;
            h8 qa0 = *(const h8*)(q);
            h8 qa1 = *(const h8*)(q + 16);
            #pragma unroll
            for (int f = 0; f < 8; ++f) {
                const _Float16* pt = &sPT[buf][(f * 32 + lid) * 40 + 8 * h];
                h8 b0 = *(const h8*)(pt);
                h8 b1 = *(const h8*)(pt + 16);
                acc[f] = __builtin_amdgcn_mfma_f32_32x32x16_f16(qa0, b0, acc[f], 0, 0, 0);
                acc[f] = __builtin_amdgcn_mfma_f32_32x32x16_f16(qa1, b1, acc[f], 0, 0, 0);
            }
            accL = __builtin_amdgcn_mfma_f32_32x32x16_f16(qa0, ones, accL, 0, 0, 0);
            accL = __builtin_amdgcn_mfma_f32_32x32x16_f16(qa1, ones, accL, 0, 0, 0);
        }
        __syncthreads();   // next buf staged + all waves done with this buf
    }

    // ---- epilogue: x_tilde = acc / l ----
    #pragma unroll
    for (int r = 0; r < 16; ++r) {
        const float inv = 1.f / accL[r];
        const int n = rowBase + (r & 3) + 8 * (r >> 2) + 4 * h;
        #pragma unroll
        for (int f = 0; f < 8; ++f)
            XT[(size_t)n * DD + f * 32 + lid] = (_Float16)(acc[f][r] * inv);
    }
}

// ---------------------------------------------------------------------------
// out: OUT[n][c] = [x | x_tilde] @ OW^T, MFMA, K=512, cols padded to 128
// ---------------------------------------------------------------------------
__global__ __launch_bounds__(256, 2) void out_kernel(
    const _Float16* __restrict__ XH, const _Float16* __restrict__ XT,
    const _Float16* __restrict__ OWsw, float* __restrict__ OUT)
{
    __shared__ __align__(16) _Float16 sW[2][32 * 256];
    const int t = threadIdx.x;
    const int wv = t >> 6, lane = t & 63, lid = lane & 31, h = lane >> 5;
    const int rowBase = blockIdx.x * 128 + wv * 32;
    const int swz = lid & 7;

    h8 xa[32];
    {
        const _Float16* x0 = XH + (size_t)(rowBase + lid) * DD + 8 * h;
        const _Float16* x1 = XT + (size_t)(rowBase + lid) * DD + 8 * h;
        #pragma unroll
        for (int kc = 0; kc < 16; ++kc) xa[kc]      = *(const h8*)(x0 + kc * 16);
        #pragma unroll
        for (int kc = 0; kc < 16; ++kc) xa[16 + kc] = *(const h8*)(x1 + kc * 16);
    }

    f32x16 acc[4];
    #pragma unroll
    for (int q = 0; q < 4; ++q)
        #pragma unroll
        for (int r = 0; r < 16; ++r) acc[q][r] = 0.f;

    #pragma unroll
    for (int i = 0; i < 4; ++i)
        gll16(OWsw + (i * 256 + t) * 8, &sW[0][(i * 256 + t) * 8]);
    __syncthreads();

    #pragma unroll
    for (int ch = 0; ch < 8; ++ch) {
        const int buf = ch & 1;
        if (ch + 1 < 8) {
            const _Float16* g = OWsw + (size_t)(ch + 1) * 8192;
            #pragma unroll
            for (int i = 0; i < 4; ++i)
                gll16(g + (i * 256 + t) * 8, &sW[buf ^ 1][(i * 256 + t) * 8]);
        }
        const int ct = ch >> 1, kh = ch & 1;
        const _Float16* wrow = &sW[buf][lid * 256];
        f32x16 a = acc[ct];
        #pragma unroll
        for (int kc = 0; kc < 16; ++kc) {
            h8 b = *(const h8*)(wrow + ((kc * 2 + h) ^ swz) * 8);
            a = __builtin_amdgcn_mfma_f32_32x32x16_f16(xa[kh * 16 + kc], b, a, 0, 0, 0);
        }
        acc[ct] = a;
        __syncthreads();
    }

    #pragma unroll
    for (int ct = 0; ct < 4; ++ct) {
        const int col = ct * 32 + lid;
        if (col < NCLSS) {
            #pragma unroll
            for (int r = 0; r < 16; ++r) {
                const int n = rowBase + (r & 3) + 8 * (r >> 2) + 4 * h;
                OUT[(size_t)n * NCLSS + col] = acc[ct][r];
            }
        }
    }
}

// ---------------------------------------------------------------------------
extern "C" void kernel_launch(void* const* d_in, const int* in_sizes, int n_in,
                              void* d_out, int out_size, void* d_ws, size_t ws_size,
                              hipStream_t stream) {
    const float* samples  = (const float*)d_in[0];
    const float* hidden_w = (const float*)d_in[1];
    const float* hidden_b = (const float*)d_in[2];
    const float* protos   = (const float*)d_in[3];
    const float* output_w = (const float*)d_in[4];
    float* out = (float*)d_out;

    char* ws = (char*)d_ws;
    _Float16* XH   = (_Float16*)(ws);                  // 26,214,400
    _Float16* XT   = (_Float16*)(ws + 26214400);       // 26,214,400
    _Float16* PHsw = (_Float16*)(ws + 52428800);       // 63*8192*2  = 1,032,192
    _Float16* PTsw = (_Float16*)(ws + 53460992);       // 63*10240*2 = 1,290,240
    _Float16* WHsw = (_Float16*)(ws + 54751232);       // 8*8192*2   =   131,072
    _Float16* OWsw = (_Float16*)(ws + 54882304);       // 8*8192*2   =   131,072
    float*    P2   = (float*)   (ws + 55013376);       // 2016*4

    p2_kernel <<<8,   256, 0, stream>>>(protos, P2);
    prep_proto<<<252, 256, 0, stream>>>(protos, PHsw, PTsw);
    prep_w    <<<32,  256, 0, stream>>>(hidden_w, WHsw);
    prep_ow   <<<32,  256, 0, stream>>>(output_w, OWsw);
    hidden_kernel<<<400, 256, 0, stream>>>(samples, WHsw, hidden_b, XH);
    attn_kernel  <<<400, 256, 0, stream>>>(XH, PHsw, PTsw, P2, XT);
    out_kernel   <<<400, 256, 0, stream>>>(XH, XT, OWsw, out);
}